// Round 1
// baseline (3260.616 us; speedup 1.0000x reference)
//
#include <hip/hip_runtime.h>

#define EPSV 1e-5f

// ---------------- init: deg=1 (self loop), pooled=0, counts=0 ----------------
__global__ __launch_bounds__(256) void init_k(float* __restrict__ degf,
                                              float* __restrict__ pooled,
                                              float* __restrict__ counts,
                                              int nnodes) {
    int i = blockIdx.x * 256 + threadIdx.x;
    if (i < nnodes) degf[i] = 1.0f;
    if (i < 64 * 128) pooled[i] = 0.0f;
    if (i < 64) counts[i] = 0.0f;
}

__global__ __launch_bounds__(256) void degcount_k(const int* __restrict__ dst,
                                                  float* __restrict__ degf,
                                                  int nedges) {
    int i = blockIdx.x * 256 + threadIdx.x;
    if (i < nedges) atomicAdd(&degf[dst[i]], 1.0f);
}

__global__ __launch_bounds__(256) void dinv_k(float* __restrict__ degf, int nnodes) {
    int i = blockIdx.x * 256 + threadIdx.x;
    if (i < nnodes) degf[i] = 1.0f / sqrtf(degf[i]);
}

// ---------------- GEMM: H[nrows][128] = X[nrows][KDIM] @ W[KDIM][128] --------
// Block: 256 threads, 32 rows x 128 cols per block, thread tile 4x4, BK=32.
template <int KDIM>
__global__ __launch_bounds__(256) void gemm_k(const float* __restrict__ X,
                                              const float* __restrict__ W,
                                              float* __restrict__ H, int nrows) {
    __shared__ float wT[32 * 128];   // [kk][c]
    __shared__ float xT[32][36];     // [r][kk], padded to 36 (16B-aligned rows)
    const int tx = threadIdx.x;
    const int tcol = tx & 31;        // col group: cols tcol*4 .. +3
    const int trow = tx >> 5;        // 0..7   : rows trow*4 .. +3
    const int row0 = blockIdx.x * 32;

    float acc[4][4];
#pragma unroll
    for (int i = 0; i < 4; i++)
#pragma unroll
        for (int j = 0; j < 4; j++) acc[i][j] = 0.0f;

    for (int k0 = 0; k0 < KDIM; k0 += 32) {
        // W tile: 4096 floats = 1024 float4, 4 per thread, coalesced
#pragma unroll
        for (int i = 0; i < 4; i++) {
            int lin4 = tx + 256 * i;
            float4 v = reinterpret_cast<const float4*>(W + k0 * 128)[lin4];
            reinterpret_cast<float4*>(wT)[lin4] = v;
        }
        // X tile: 32 rows x 32 k = 256 float4, 1 per thread
        {
            int r = tx >> 3;
            int kk4 = (tx & 7) * 4;
            int row = row0 + r;
            float4 v = make_float4(0.f, 0.f, 0.f, 0.f);
            if (row < nrows)
                v = *reinterpret_cast<const float4*>(X + (size_t)row * KDIM + k0 + kk4);
            *reinterpret_cast<float4*>(&xT[r][kk4]) = v;
        }
        __syncthreads();
#pragma unroll
        for (int kk = 0; kk < 32; kk++) {
            float4 wv = *reinterpret_cast<const float4*>(wT + kk * 128 + tcol * 4);
            float xv[4];
#pragma unroll
            for (int i = 0; i < 4; i++) xv[i] = xT[trow * 4 + i][kk];
#pragma unroll
            for (int i = 0; i < 4; i++) {
                acc[i][0] += xv[i] * wv.x;
                acc[i][1] += xv[i] * wv.y;
                acc[i][2] += xv[i] * wv.z;
                acc[i][3] += xv[i] * wv.w;
            }
        }
        __syncthreads();
    }
#pragma unroll
    for (int i = 0; i < 4; i++) {
        int row = row0 + trow * 4 + i;
        if (row < nrows) {
            float4 v = make_float4(acc[i][0], acc[i][1], acc[i][2], acc[i][3]);
            *reinterpret_cast<float4*>(H + (size_t)row * 128 + tcol * 4) = v;
        }
    }
}

// ---------------- self-loop init: OUT[i][c] = H[i][c] * dinv[i]^2 ------------
__global__ __launch_bounds__(256) void selfloop_k(const float* __restrict__ H,
                                                  const float* __restrict__ dinv,
                                                  float* __restrict__ OUT, int n) {
    int i = blockIdx.x * 256 + threadIdx.x;
    if (i >= n) return;
    float di = dinv[i >> 7];
    OUT[i] = H[i] * di * di;
}

// ---------------- edge scatter: OUT[dst] += H[src] * dinv[src]*dinv[dst] -----
// 32 lanes per edge, float4 (4 channels) per lane, grid-stride over edges.
__global__ __launch_bounds__(256) void scatter_k(const float* __restrict__ H,
                                                 const int* __restrict__ src,
                                                 const int* __restrict__ dst,
                                                 const float* __restrict__ dinv,
                                                 float* __restrict__ OUT,
                                                 int nedges, int eslots) {
    int t = blockIdx.x * 256 + threadIdx.x;
    int l = t & 31;
    int e = t >> 5;
    for (; e < nedges; e += eslots) {
        int s = src[e];
        int d = dst[e];
        float norm = dinv[s] * dinv[d];
        float4 hv = *reinterpret_cast<const float4*>(H + (size_t)s * 128 + l * 4);
        float* op = OUT + (size_t)d * 128 + l * 4;
        atomicAdd(op + 0, hv.x * norm);
        atomicAdd(op + 1, hv.y * norm);
        atomicAdd(op + 2, hv.z * norm);
        atomicAdd(op + 3, hv.w * norm);
    }
}

// ---------------- BN(eval) + ReLU, in place -----------------------------
__global__ __launch_bounds__(256) void bn_relu_k(float* __restrict__ V,
                                                 const float* __restrict__ b,
                                                 const float* __restrict__ gamma,
                                                 const float* __restrict__ beta,
                                                 const float* __restrict__ rm,
                                                 const float* __restrict__ rv, int n) {
    int i = blockIdx.x * 256 + threadIdx.x;
    if (i >= n) return;
    int c = i & 127;
    float v = V[i] + b[c];
    v = (v - rm[c]) * (1.0f / sqrtf(rv[c] + EPSV)) * gamma[c] + beta[c];
    V[i] = fmaxf(v, 0.0f);
}

// ---------------- BN + ReLU + mean-pool accumulate (layer 2) -----------------
__global__ __launch_bounds__(256) void bn_relu_pool_k(const float* __restrict__ V,
                                                      const float* __restrict__ b,
                                                      const float* __restrict__ gamma,
                                                      const float* __restrict__ beta,
                                                      const float* __restrict__ rm,
                                                      const float* __restrict__ rv,
                                                      const int* __restrict__ batch,
                                                      float* __restrict__ pooled,
                                                      float* __restrict__ counts, int n) {
    int i = blockIdx.x * 256 + threadIdx.x;
    if (i >= n) return;
    int c = i & 127;
    int node = i >> 7;
    float v = V[i] + b[c];
    v = (v - rm[c]) * (1.0f / sqrtf(rv[c] + EPSV)) * gamma[c] + beta[c];
    v = fmaxf(v, 0.0f);
    int g = batch[node];
    atomicAdd(&pooled[g * 128 + c], v);
    if (c == 0) atomicAdd(&counts[g], 1.0f);
}

// ---------------- final: out[g][o] = mean(pooled[g]) @ Wl + bl ---------------
__global__ __launch_bounds__(128) void final_k(const float* __restrict__ pooled,
                                               const float* __restrict__ counts,
                                               const float* __restrict__ Wl,
                                               const float* __restrict__ bl,
                                               float* __restrict__ out) {
    int tx = threadIdx.x;
    if (tx >= 128) return;
    int g = tx >> 1, o = tx & 1;
    float cnt = fmaxf(counts[g], 1.0f);
    float s = 0.0f;
#pragma unroll 8
    for (int c = 0; c < 128; c++) s += pooled[g * 128 + c] * Wl[c * 2 + o];
    out[tx] = s / cnt + bl[o];
}

extern "C" void kernel_launch(void* const* d_in, const int* in_sizes, int n_in,
                              void* d_out, int out_size, void* d_ws, size_t ws_size,
                              hipStream_t stream) {
    const float* x      = (const float*)d_in[0];
    const int*   ei     = (const int*)d_in[1];
    const int*   batch  = (const int*)d_in[2];
    const float* W1     = (const float*)d_in[3];
    const float* b1     = (const float*)d_in[4];
    const float* gamma1 = (const float*)d_in[5];
    const float* beta1  = (const float*)d_in[6];
    const float* rm1    = (const float*)d_in[7];
    const float* rv1    = (const float*)d_in[8];
    const float* W2     = (const float*)d_in[9];
    const float* b2     = (const float*)d_in[10];
    const float* gamma2 = (const float*)d_in[11];
    const float* beta2  = (const float*)d_in[12];
    const float* rm2    = (const float*)d_in[13];
    const float* rv2    = (const float*)d_in[14];
    const float* Wl     = (const float*)d_in[15];
    const float* bl     = (const float*)d_in[16];
    float* out = (float*)d_out;

    const int nnodes = in_sizes[2];
    const int nedges = in_sizes[1] / 2;
    const int nfeat  = nnodes * 128;
    const int* srcp = ei;
    const int* dstp = ei + nedges;

    float* wsA    = (float*)d_ws;                       // [nnodes*128] h (gemm out)
    float* wsB    = wsA + (size_t)nnodes * 128;         // [nnodes*128] conv out
    float* degf   = wsB + (size_t)nnodes * 128;         // [nnodes] deg -> dinv
    float* pooled = degf + nnodes;                      // [64*128]
    float* counts = pooled + 64 * 128;                  // [64]

    dim3 blk(256);
    const int gNodes = (nnodes + 255) / 256;
    const int gEdges = (nedges + 255) / 256;
    const int gFeat  = (nfeat + 255) / 256;
    const int gGemm  = (nnodes + 31) / 32;
    const int scatterBlocks = 25000;
    const int eslots = scatterBlocks * 256 / 32;

    init_k<<<gNodes, blk, 0, stream>>>(degf, pooled, counts, nnodes);
    degcount_k<<<gEdges, blk, 0, stream>>>(dstp, degf, nedges);
    dinv_k<<<gNodes, blk, 0, stream>>>(degf, nnodes);

    // ---- layer 1 ----
    gemm_k<512><<<gGemm, blk, 0, stream>>>(x, W1, wsA, nnodes);
    selfloop_k<<<gFeat, blk, 0, stream>>>(wsA, degf, wsB, nfeat);
    scatter_k<<<scatterBlocks, blk, 0, stream>>>(wsA, srcp, dstp, degf, wsB, nedges, eslots);
    bn_relu_k<<<gFeat, blk, 0, stream>>>(wsB, b1, gamma1, beta1, rm1, rv1, nfeat);

    // ---- layer 2 ----
    gemm_k<128><<<gGemm, blk, 0, stream>>>(wsB, W2, wsA, nnodes);
    selfloop_k<<<gFeat, blk, 0, stream>>>(wsA, degf, wsB, nfeat);
    scatter_k<<<scatterBlocks, blk, 0, stream>>>(wsA, srcp, dstp, degf, wsB, nedges, eslots);
    bn_relu_pool_k<<<gFeat, blk, 0, stream>>>(wsB, b2, gamma2, beta2, rm2, rv2,
                                              batch, pooled, counts, nfeat);

    // ---- readout ----
    final_k<<<1, 128, 0, stream>>>(pooled, counts, Wl, bl, out);
}

// Round 2
// 721.788 us; speedup vs baseline: 4.5174x; 4.5174x over previous
//
#include <hip/hip_runtime.h>

#define EPSV 1e-5f

// ---------------- init: cnt=0, pooled=0, counts=0 ----------------
__global__ __launch_bounds__(256) void init_k(int* __restrict__ cnt,
                                              float* __restrict__ pooled,
                                              float* __restrict__ counts,
                                              int nnodes) {
    int i = blockIdx.x * 256 + threadIdx.x;
    if (i < nnodes) cnt[i] = 0;
    if (i < 64 * 128) pooled[i] = 0.0f;
    if (i < 64) counts[i] = 0.0f;
}

// per-graph node counts (for mean pool)
__global__ __launch_bounds__(256) void counts_k(const int* __restrict__ batch,
                                                float* __restrict__ counts, int nnodes) {
    int i = blockIdx.x * 256 + threadIdx.x;
    if (i < nnodes) atomicAdd(&counts[batch[i]], 1.0f);
}

__global__ __launch_bounds__(256) void degcount_k(const int* __restrict__ dst,
                                                  int* __restrict__ cnt,
                                                  int nedges) {
    int i = blockIdx.x * 256 + threadIdx.x;
    if (i < nedges) atomicAdd(&cnt[dst[i]], 1);
}

__global__ __launch_bounds__(256) void dinv_k(const int* __restrict__ cnt,
                                              float* __restrict__ dinv, int nnodes) {
    int i = blockIdx.x * 256 + threadIdx.x;
    if (i < nnodes) dinv[i] = rsqrtf(1.0f + (float)cnt[i]);
}

// ---------------- exclusive scan of cnt[] -> rowptr[] (3 kernels) ------------
// scan1: per-block (1024 elems) exclusive scan + block totals
__global__ __launch_bounds__(256) void scan1_k(const int* __restrict__ cnt,
                                               int* __restrict__ rowptr,
                                               int* __restrict__ bsum, int n) {
    __shared__ int sh[256];
    const int tx = threadIdx.x;
    const int base = blockIdx.x * 1024;
    int v[4];
    int s = 0;
#pragma unroll
    for (int j = 0; j < 4; j++) {
        int idx = base + tx * 4 + j;
        v[j] = (idx < n) ? cnt[idx] : 0;
        s += v[j];
    }
    sh[tx] = s;
    __syncthreads();
#pragma unroll
    for (int off = 1; off < 256; off <<= 1) {
        int t = (tx >= off) ? sh[tx - off] : 0;
        __syncthreads();
        sh[tx] += t;
        __syncthreads();
    }
    int run = sh[tx] - s;  // exclusive prefix of this thread's chunk
#pragma unroll
    for (int j = 0; j < 4; j++) {
        int idx = base + tx * 4 + j;
        if (idx < n) rowptr[idx] = run;
        run += v[j];
    }
    if (tx == 255) bsum[blockIdx.x] = sh[255];
}

// scan2: exclusive scan of block sums (nb <= 64), in place
__global__ __launch_bounds__(64) void scan2_k(int* __restrict__ bsum, int nb) {
    __shared__ int sh[64];
    const int tx = threadIdx.x;
    int v = (tx < nb) ? bsum[tx] : 0;
    sh[tx] = v;
    __syncthreads();
#pragma unroll
    for (int off = 1; off < 64; off <<= 1) {
        int t = (tx >= off) ? sh[tx - off] : 0;
        __syncthreads();
        sh[tx] += t;
        __syncthreads();
    }
    if (tx < nb) bsum[tx] = sh[tx] - v;
}

// scan3: add block offsets, init cursor, write rowptr[n]
__global__ __launch_bounds__(256) void scan3_k(int* __restrict__ rowptr,
                                               int* __restrict__ cur,
                                               const int* __restrict__ bsum,
                                               int n, int nedges) {
    const int tx = threadIdx.x;
    const int base = blockIdx.x * 1024;
    int off = bsum[blockIdx.x];
#pragma unroll
    for (int j = 0; j < 4; j++) {
        int idx = base + tx * 4 + j;
        if (idx < n) {
            int r = rowptr[idx] + off;
            rowptr[idx] = r;
            cur[idx] = r;
        }
    }
    if (blockIdx.x == 0 && tx == 0) rowptr[n] = nedges;
}

// fill: edge_src grouped by dst
__global__ __launch_bounds__(256) void fill_k(const int* __restrict__ src,
                                              const int* __restrict__ dst,
                                              int* __restrict__ cur,
                                              int* __restrict__ esrc, int nedges) {
    int i = blockIdx.x * 256 + threadIdx.x;
    if (i >= nedges) return;
    int pos = atomicAdd(&cur[dst[i]], 1);
    esrc[pos] = src[i];
}

// ---------------- GEMM: H[nrows][128] = X[nrows][KDIM] @ W[KDIM][128] --------
template <int KDIM>
__global__ __launch_bounds__(256) void gemm_k(const float* __restrict__ X,
                                              const float* __restrict__ W,
                                              float* __restrict__ H, int nrows) {
    __shared__ float wT[32 * 128];   // [kk][c]
    __shared__ float xT[32][36];     // [r][kk], padded
    const int tx = threadIdx.x;
    const int tcol = tx & 31;
    const int trow = tx >> 5;
    const int row0 = blockIdx.x * 32;

    float acc[4][4];
#pragma unroll
    for (int i = 0; i < 4; i++)
#pragma unroll
        for (int j = 0; j < 4; j++) acc[i][j] = 0.0f;

    for (int k0 = 0; k0 < KDIM; k0 += 32) {
#pragma unroll
        for (int i = 0; i < 4; i++) {
            int lin4 = tx + 256 * i;
            float4 v = reinterpret_cast<const float4*>(W + k0 * 128)[lin4];
            reinterpret_cast<float4*>(wT)[lin4] = v;
        }
        {
            int r = tx >> 3;
            int kk4 = (tx & 7) * 4;
            int row = row0 + r;
            float4 v = make_float4(0.f, 0.f, 0.f, 0.f);
            if (row < nrows)
                v = *reinterpret_cast<const float4*>(X + (size_t)row * KDIM + k0 + kk4);
            *reinterpret_cast<float4*>(&xT[r][kk4]) = v;
        }
        __syncthreads();
#pragma unroll
        for (int kk = 0; kk < 32; kk++) {
            float4 wv = *reinterpret_cast<const float4*>(wT + kk * 128 + tcol * 4);
            float xv[4];
#pragma unroll
            for (int i = 0; i < 4; i++) xv[i] = xT[trow * 4 + i][kk];
#pragma unroll
            for (int i = 0; i < 4; i++) {
                acc[i][0] += xv[i] * wv.x;
                acc[i][1] += xv[i] * wv.y;
                acc[i][2] += xv[i] * wv.z;
                acc[i][3] += xv[i] * wv.w;
            }
        }
        __syncthreads();
    }
#pragma unroll
    for (int i = 0; i < 4; i++) {
        int row = row0 + trow * 4 + i;
        if (row < nrows) {
            float4 v = make_float4(acc[i][0], acc[i][1], acc[i][2], acc[i][3]);
            *reinterpret_cast<float4*>(H + (size_t)row * 128 + tcol * 4) = v;
        }
    }
}

// ---------------- fused aggregate: CSR gather + selfloop + bias + BN + ReLU --
// LAYER 1: write node row to OUT.  LAYER 2: atomicAdd into pooled[batch[node]].
template <int LAYER>
__global__ __launch_bounds__(256) void agg_k(const float* __restrict__ H,
                                             const int* __restrict__ rowptr,
                                             const int* __restrict__ esrc,
                                             const float* __restrict__ dinv,
                                             const float* __restrict__ bias,
                                             const float* __restrict__ gamma,
                                             const float* __restrict__ beta,
                                             const float* __restrict__ rm,
                                             const float* __restrict__ rv,
                                             float* __restrict__ OUT,
                                             const int* __restrict__ batch,
                                             float* __restrict__ pooled,
                                             int nnodes) {
    const int node = blockIdx.x * 4 + (threadIdx.x >> 6);
    if (node >= nnodes) return;
    const int l = threadIdx.x & 63;
    const int c = l * 2;
    const float dn = dinv[node];

    // self-loop: h[node] * dinv[node]^2
    float2 hv = *reinterpret_cast<const float2*>(H + (size_t)node * 128 + c);
    float2 acc = make_float2(hv.x * dn * dn, hv.y * dn * dn);
    float2 acc2 = make_float2(0.f, 0.f);

    const int beg = rowptr[node], end = rowptr[node + 1];
    int j = beg;
    for (; j + 1 < end; j += 2) {
        int s0 = esrc[j], s1 = esrc[j + 1];
        float n0 = dinv[s0] * dn, n1 = dinv[s1] * dn;
        float2 h0 = *reinterpret_cast<const float2*>(H + (size_t)s0 * 128 + c);
        float2 h1 = *reinterpret_cast<const float2*>(H + (size_t)s1 * 128 + c);
        acc.x += h0.x * n0;  acc.y += h0.y * n0;
        acc2.x += h1.x * n1; acc2.y += h1.y * n1;
    }
    if (j < end) {
        int s0 = esrc[j];
        float n0 = dinv[s0] * dn;
        float2 h0 = *reinterpret_cast<const float2*>(H + (size_t)s0 * 128 + c);
        acc.x += h0.x * n0; acc.y += h0.y * n0;
    }
    acc.x += acc2.x; acc.y += acc2.y;

    // bias + BN(eval) + ReLU for channels c, c+1
    float v0 = acc.x + bias[c];
    float v1 = acc.y + bias[c + 1];
    v0 = (v0 - rm[c])     * rsqrtf(rv[c] + EPSV)     * gamma[c]     + beta[c];
    v1 = (v1 - rm[c + 1]) * rsqrtf(rv[c + 1] + EPSV) * gamma[c + 1] + beta[c + 1];
    v0 = fmaxf(v0, 0.0f);
    v1 = fmaxf(v1, 0.0f);

    if (LAYER == 1) {
        *reinterpret_cast<float2*>(OUT + (size_t)node * 128 + c) = make_float2(v0, v1);
    } else {
        int g = batch[node];
        atomicAdd(&pooled[g * 128 + c], v0);
        atomicAdd(&pooled[g * 128 + c + 1], v1);
    }
}

// ---------------- final: out[g][o] = mean(pooled[g]) @ Wl + bl ---------------
__global__ __launch_bounds__(128) void final_k(const float* __restrict__ pooled,
                                               const float* __restrict__ counts,
                                               const float* __restrict__ Wl,
                                               const float* __restrict__ bl,
                                               float* __restrict__ out) {
    int tx = threadIdx.x;
    int g = tx >> 1, o = tx & 1;
    float cnt = fmaxf(counts[g], 1.0f);
    float s = 0.0f;
#pragma unroll 8
    for (int c = 0; c < 128; c++) s += pooled[g * 128 + c] * Wl[c * 2 + o];
    out[tx] = s / cnt + bl[o];
}

extern "C" void kernel_launch(void* const* d_in, const int* in_sizes, int n_in,
                              void* d_out, int out_size, void* d_ws, size_t ws_size,
                              hipStream_t stream) {
    const float* x      = (const float*)d_in[0];
    const int*   ei     = (const int*)d_in[1];
    const int*   batch  = (const int*)d_in[2];
    const float* W1     = (const float*)d_in[3];
    const float* b1     = (const float*)d_in[4];
    const float* gamma1 = (const float*)d_in[5];
    const float* beta1  = (const float*)d_in[6];
    const float* rm1    = (const float*)d_in[7];
    const float* rv1    = (const float*)d_in[8];
    const float* W2     = (const float*)d_in[9];
    const float* b2     = (const float*)d_in[10];
    const float* gamma2 = (const float*)d_in[11];
    const float* beta2  = (const float*)d_in[12];
    const float* rm2    = (const float*)d_in[13];
    const float* rv2    = (const float*)d_in[14];
    const float* Wl     = (const float*)d_in[15];
    const float* bl     = (const float*)d_in[16];
    float* out = (float*)d_out;

    const int nnodes = in_sizes[2];
    const int nedges = in_sizes[1] / 2;
    const int* srcp = ei;
    const int* dstp = ei + nedges;

    float* wsA    = (float*)d_ws;                       // [nnodes*128]
    float* wsB    = wsA + (size_t)nnodes * 128;         // [nnodes*128]
    float* dinv   = wsB + (size_t)nnodes * 128;         // [nnodes]
    float* pooled = dinv + nnodes;                      // [64*128]
    float* counts = pooled + 64 * 128;                  // [64]
    int*   cnt    = (int*)(counts + 64);                // [nnodes]
    int*   rowptr = cnt + nnodes;                       // [nnodes+1]
    int*   cur    = rowptr + nnodes + 1;                // [nnodes]
    int*   bsum   = cur + nnodes;                       // [64]
    int*   esrc   = bsum + 64;                          // [nedges]

    dim3 blk(256);
    const int gNodes = (nnodes + 255) / 256;
    const int gEdges = (nedges + 255) / 256;
    const int gGemm  = (nnodes + 31) / 32;
    const int gAgg   = (nnodes + 3) / 4;
    const int nScanB = (nnodes + 1023) / 1024;

    // ---- graph preprocessing (CSR by dst) ----
    init_k<<<gNodes, blk, 0, stream>>>(cnt, pooled, counts, nnodes);
    counts_k<<<gNodes, blk, 0, stream>>>(batch, counts, nnodes);
    degcount_k<<<gEdges, blk, 0, stream>>>(dstp, cnt, nedges);
    dinv_k<<<gNodes, blk, 0, stream>>>(cnt, dinv, nnodes);
    scan1_k<<<nScanB, blk, 0, stream>>>(cnt, rowptr, bsum, nnodes);
    scan2_k<<<1, 64, 0, stream>>>(bsum, nScanB);
    scan3_k<<<nScanB, blk, 0, stream>>>(rowptr, cur, bsum, nnodes, nedges);
    fill_k<<<gEdges, blk, 0, stream>>>(srcp, dstp, cur, esrc, nedges);

    // ---- layer 1: GEMM + fused aggregate/BN/ReLU ----
    gemm_k<512><<<gGemm, blk, 0, stream>>>(x, W1, wsA, nnodes);
    agg_k<1><<<gAgg, blk, 0, stream>>>(wsA, rowptr, esrc, dinv, b1, gamma1, beta1,
                                       rm1, rv1, wsB, batch, pooled, nnodes);

    // ---- layer 2: GEMM + fused aggregate/BN/ReLU/pool ----
    gemm_k<128><<<gGemm, blk, 0, stream>>>(wsB, W2, wsA, nnodes);
    agg_k<2><<<gAgg, blk, 0, stream>>>(wsA, rowptr, esrc, dinv, b2, gamma2, beta2,
                                       rm2, rv2, nullptr, batch, pooled, nnodes);

    // ---- readout ----
    final_k<<<1, 128, 0, stream>>>(pooled, counts, Wl, bl, out);
}

// Round 3
// 502.435 us; speedup vs baseline: 6.4896x; 1.4366x over previous
//
#include <hip/hip_runtime.h>

#define EPSV 1e-5f

// ---------------- init: cnt=0 ----------------
__global__ __launch_bounds__(256) void init_k(int* __restrict__ cnt, int nnodes) {
    int i = blockIdx.x * 256 + threadIdx.x;
    if (i < nnodes) cnt[i] = 0;
}

// ---------------- graph segment starts via binary search on sorted batch ----
__global__ __launch_bounds__(128) void gstart_k(const int* __restrict__ batch,
                                                int* __restrict__ gstart,
                                                int nnodes, int ngraphs) {
    int g = threadIdx.x;
    if (g > ngraphs) return;
    // lower_bound: first i with batch[i] >= g
    int lo = 0, hi = nnodes;
    while (lo < hi) {
        int mid = (lo + hi) >> 1;
        if (batch[mid] < g) lo = mid + 1; else hi = mid;
    }
    gstart[g] = lo;
}

__global__ __launch_bounds__(256) void degcount_k(const int* __restrict__ dst,
                                                  int* __restrict__ cnt,
                                                  int nedges) {
    int i = blockIdx.x * 256 + threadIdx.x;
    if (i < nedges) atomicAdd(&cnt[dst[i]], 1);
}

__global__ __launch_bounds__(256) void dinv_k(const int* __restrict__ cnt,
                                              float* __restrict__ dinv, int nnodes) {
    int i = blockIdx.x * 256 + threadIdx.x;
    if (i < nnodes) dinv[i] = rsqrtf(1.0f + (float)cnt[i]);
}

// ---------------- exclusive scan of cnt[] -> rowptr[] (3 kernels) ------------
__global__ __launch_bounds__(256) void scan1_k(const int* __restrict__ cnt,
                                               int* __restrict__ rowptr,
                                               int* __restrict__ bsum, int n) {
    __shared__ int sh[256];
    const int tx = threadIdx.x;
    const int base = blockIdx.x * 1024;
    int v[4];
    int s = 0;
#pragma unroll
    for (int j = 0; j < 4; j++) {
        int idx = base + tx * 4 + j;
        v[j] = (idx < n) ? cnt[idx] : 0;
        s += v[j];
    }
    sh[tx] = s;
    __syncthreads();
#pragma unroll
    for (int off = 1; off < 256; off <<= 1) {
        int t = (tx >= off) ? sh[tx - off] : 0;
        __syncthreads();
        sh[tx] += t;
        __syncthreads();
    }
    int run = sh[tx] - s;
#pragma unroll
    for (int j = 0; j < 4; j++) {
        int idx = base + tx * 4 + j;
        if (idx < n) rowptr[idx] = run;
        run += v[j];
    }
    if (tx == 255) bsum[blockIdx.x] = sh[255];
}

__global__ __launch_bounds__(64) void scan2_k(int* __restrict__ bsum, int nb) {
    __shared__ int sh[64];
    const int tx = threadIdx.x;
    int v = (tx < nb) ? bsum[tx] : 0;
    sh[tx] = v;
    __syncthreads();
#pragma unroll
    for (int off = 1; off < 64; off <<= 1) {
        int t = (tx >= off) ? sh[tx - off] : 0;
        __syncthreads();
        sh[tx] += t;
        __syncthreads();
    }
    if (tx < nb) bsum[tx] = sh[tx] - v;
}

__global__ __launch_bounds__(256) void scan3_k(int* __restrict__ rowptr,
                                               int* __restrict__ cur,
                                               const int* __restrict__ bsum,
                                               int n, int nedges) {
    const int tx = threadIdx.x;
    const int base = blockIdx.x * 1024;
    int off = bsum[blockIdx.x];
#pragma unroll
    for (int j = 0; j < 4; j++) {
        int idx = base + tx * 4 + j;
        if (idx < n) {
            int r = rowptr[idx] + off;
            rowptr[idx] = r;
            cur[idx] = r;
        }
    }
    if (blockIdx.x == 0 && tx == 0) rowptr[n] = nedges;
}

__global__ __launch_bounds__(256) void fill_k(const int* __restrict__ src,
                                              const int* __restrict__ dst,
                                              int* __restrict__ cur,
                                              int* __restrict__ esrc, int nedges) {
    int i = blockIdx.x * 256 + threadIdx.x;
    if (i >= nedges) return;
    int pos = atomicAdd(&cur[dst[i]], 1);
    esrc[pos] = src[i];
}

// ---------------- GEMM: H[nrows][128] = X[nrows][KDIM] @ W[KDIM][128] --------
template <int KDIM>
__global__ __launch_bounds__(256) void gemm_k(const float* __restrict__ X,
                                              const float* __restrict__ W,
                                              float* __restrict__ H, int nrows) {
    __shared__ float wT[32 * 128];
    __shared__ float xT[32][36];
    const int tx = threadIdx.x;
    const int tcol = tx & 31;
    const int trow = tx >> 5;
    const int row0 = blockIdx.x * 32;

    float acc[4][4];
#pragma unroll
    for (int i = 0; i < 4; i++)
#pragma unroll
        for (int j = 0; j < 4; j++) acc[i][j] = 0.0f;

    for (int k0 = 0; k0 < KDIM; k0 += 32) {
#pragma unroll
        for (int i = 0; i < 4; i++) {
            int lin4 = tx + 256 * i;
            float4 v = reinterpret_cast<const float4*>(W + k0 * 128)[lin4];
            reinterpret_cast<float4*>(wT)[lin4] = v;
        }
        {
            int r = tx >> 3;
            int kk4 = (tx & 7) * 4;
            int row = row0 + r;
            float4 v = make_float4(0.f, 0.f, 0.f, 0.f);
            if (row < nrows)
                v = *reinterpret_cast<const float4*>(X + (size_t)row * KDIM + k0 + kk4);
            *reinterpret_cast<float4*>(&xT[r][kk4]) = v;
        }
        __syncthreads();
#pragma unroll
        for (int kk = 0; kk < 32; kk++) {
            float4 wv = *reinterpret_cast<const float4*>(wT + kk * 128 + tcol * 4);
            float xv[4];
#pragma unroll
            for (int i = 0; i < 4; i++) xv[i] = xT[trow * 4 + i][kk];
#pragma unroll
            for (int i = 0; i < 4; i++) {
                acc[i][0] += xv[i] * wv.x;
                acc[i][1] += xv[i] * wv.y;
                acc[i][2] += xv[i] * wv.z;
                acc[i][3] += xv[i] * wv.w;
            }
        }
        __syncthreads();
    }
#pragma unroll
    for (int i = 0; i < 4; i++) {
        int row = row0 + trow * 4 + i;
        if (row < nrows) {
            float4 v = make_float4(acc[i][0], acc[i][1], acc[i][2], acc[i][3]);
            *reinterpret_cast<float4*>(H + (size_t)row * 128 + tcol * 4) = v;
        }
    }
}

// ---------------- fused aggregate: CSR gather + selfloop + bias + BN + ReLU --
__global__ __launch_bounds__(256) void agg_k(const float* __restrict__ H,
                                             const int* __restrict__ rowptr,
                                             const int* __restrict__ esrc,
                                             const float* __restrict__ dinv,
                                             const float* __restrict__ bias,
                                             const float* __restrict__ gamma,
                                             const float* __restrict__ beta,
                                             const float* __restrict__ rm,
                                             const float* __restrict__ rv,
                                             float* __restrict__ OUT,
                                             int nnodes) {
    const int node = blockIdx.x * 4 + (threadIdx.x >> 6);
    if (node >= nnodes) return;
    const int l = threadIdx.x & 63;
    const int c = l * 2;
    const float dn = dinv[node];

    float2 hv = *reinterpret_cast<const float2*>(H + (size_t)node * 128 + c);
    float2 acc = make_float2(hv.x * dn * dn, hv.y * dn * dn);
    float2 acc2 = make_float2(0.f, 0.f);

    const int beg = rowptr[node], end = rowptr[node + 1];
    int j = beg;
    for (; j + 1 < end; j += 2) {
        int s0 = esrc[j], s1 = esrc[j + 1];
        float n0 = dinv[s0] * dn, n1 = dinv[s1] * dn;
        float2 h0 = *reinterpret_cast<const float2*>(H + (size_t)s0 * 128 + c);
        float2 h1 = *reinterpret_cast<const float2*>(H + (size_t)s1 * 128 + c);
        acc.x += h0.x * n0;  acc.y += h0.y * n0;
        acc2.x += h1.x * n1; acc2.y += h1.y * n1;
    }
    if (j < end) {
        int s0 = esrc[j];
        float n0 = dinv[s0] * dn;
        float2 h0 = *reinterpret_cast<const float2*>(H + (size_t)s0 * 128 + c);
        acc.x += h0.x * n0; acc.y += h0.y * n0;
    }
    acc.x += acc2.x; acc.y += acc2.y;

    float v0 = acc.x + bias[c];
    float v1 = acc.y + bias[c + 1];
    v0 = (v0 - rm[c])     * rsqrtf(rv[c] + EPSV)     * gamma[c]     + beta[c];
    v1 = (v1 - rm[c + 1]) * rsqrtf(rv[c + 1] + EPSV) * gamma[c + 1] + beta[c + 1];
    v0 = fmaxf(v0, 0.0f);
    v1 = fmaxf(v1, 0.0f);

    *reinterpret_cast<float2*>(OUT + (size_t)node * 128 + c) = make_float2(v0, v1);
}

// ---------------- mean pool over contiguous graph segments ------------------
// one block per graph; 256 threads = 2 node-lanes x 128 channels
__global__ __launch_bounds__(256) void pool_k(const float* __restrict__ V,
                                              const int* __restrict__ gstart,
                                              float* __restrict__ pooled) {
    __shared__ float sh[256];
    const int g = blockIdx.x;
    const int tx = threadIdx.x;
    const int ch = tx & 127;
    const int sub = tx >> 7;
    const int beg = gstart[g], end = gstart[g + 1];
    float acc = 0.0f;
    for (int i = beg + sub; i < end; i += 2)
        acc += V[(size_t)i * 128 + ch];
    sh[tx] = acc;
    __syncthreads();
    if (tx < 128) {
        float tot = sh[tx] + sh[tx + 128];
        float cnt = fmaxf((float)(end - beg), 1.0f);
        pooled[g * 128 + tx] = tot / cnt;
    }
}

// ---------------- final: out[g][o] = pooled[g] @ Wl + bl ---------------------
__global__ __launch_bounds__(128) void final_k(const float* __restrict__ pooled,
                                               const float* __restrict__ Wl,
                                               const float* __restrict__ bl,
                                               float* __restrict__ out) {
    int tx = threadIdx.x;
    int g = tx >> 1, o = tx & 1;
    float s = 0.0f;
#pragma unroll 8
    for (int c = 0; c < 128; c++) s += pooled[g * 128 + c] * Wl[c * 2 + o];
    out[tx] = s + bl[o];
}

extern "C" void kernel_launch(void* const* d_in, const int* in_sizes, int n_in,
                              void* d_out, int out_size, void* d_ws, size_t ws_size,
                              hipStream_t stream) {
    const float* x      = (const float*)d_in[0];
    const int*   ei     = (const int*)d_in[1];
    const int*   batch  = (const int*)d_in[2];
    const float* W1     = (const float*)d_in[3];
    const float* b1     = (const float*)d_in[4];
    const float* gamma1 = (const float*)d_in[5];
    const float* beta1  = (const float*)d_in[6];
    const float* rm1    = (const float*)d_in[7];
    const float* rv1    = (const float*)d_in[8];
    const float* W2     = (const float*)d_in[9];
    const float* b2     = (const float*)d_in[10];
    const float* gamma2 = (const float*)d_in[11];
    const float* beta2  = (const float*)d_in[12];
    const float* rm2    = (const float*)d_in[13];
    const float* rv2    = (const float*)d_in[14];
    const float* Wl     = (const float*)d_in[15];
    const float* bl     = (const float*)d_in[16];
    float* out = (float*)d_out;

    const int nnodes  = in_sizes[2];
    const int nedges  = in_sizes[1] / 2;
    const int ngraphs = 64;
    const int* srcp = ei;
    const int* dstp = ei + nedges;

    float* wsA    = (float*)d_ws;                       // [nnodes*128]
    float* wsB    = wsA + (size_t)nnodes * 128;         // [nnodes*128]
    float* dinv   = wsB + (size_t)nnodes * 128;         // [nnodes]
    float* pooled = dinv + nnodes;                      // [64*128]
    int*   cnt    = (int*)(pooled + 64 * 128);          // [nnodes]
    int*   rowptr = cnt + nnodes;                       // [nnodes+1]
    int*   cur    = rowptr + nnodes + 1;                // [nnodes]
    int*   bsum   = cur + nnodes;                       // [64]
    int*   gstart = bsum + 64;                          // [65]
    int*   esrc   = gstart + 65;                        // [nedges]

    dim3 blk(256);
    const int gNodes = (nnodes + 255) / 256;
    const int gEdges = (nedges + 255) / 256;
    const int gGemm  = (nnodes + 31) / 32;
    const int gAgg   = (nnodes + 3) / 4;
    const int nScanB = (nnodes + 1023) / 1024;

    // ---- graph preprocessing (CSR by dst + graph segments) ----
    init_k<<<gNodes, blk, 0, stream>>>(cnt, nnodes);
    gstart_k<<<1, 128, 0, stream>>>(batch, gstart, nnodes, ngraphs);
    degcount_k<<<gEdges, blk, 0, stream>>>(dstp, cnt, nedges);
    dinv_k<<<gNodes, blk, 0, stream>>>(cnt, dinv, nnodes);
    scan1_k<<<nScanB, blk, 0, stream>>>(cnt, rowptr, bsum, nnodes);
    scan2_k<<<1, 64, 0, stream>>>(bsum, nScanB);
    scan3_k<<<nScanB, blk, 0, stream>>>(rowptr, cur, bsum, nnodes, nedges);
    fill_k<<<gEdges, blk, 0, stream>>>(srcp, dstp, cur, esrc, nedges);

    // ---- layer 1: GEMM + fused aggregate/BN/ReLU ----
    gemm_k<512><<<gGemm, blk, 0, stream>>>(x, W1, wsA, nnodes);
    agg_k<<<gAgg, blk, 0, stream>>>(wsA, rowptr, esrc, dinv, b1, gamma1, beta1,
                                    rm1, rv1, wsB, nnodes);

    // ---- layer 2: GEMM + fused aggregate/BN/ReLU ----
    gemm_k<128><<<gGemm, blk, 0, stream>>>(wsB, W2, wsA, nnodes);
    agg_k<<<gAgg, blk, 0, stream>>>(wsA, rowptr, esrc, dinv, b2, gamma2, beta2,
                                    rm2, rv2, wsB, nnodes);

    // ---- readout ----
    pool_k<<<ngraphs, blk, 0, stream>>>(wsB, gstart, pooled);
    final_k<<<1, 128, 0, stream>>>(pooled, Wl, bl, out);
}